// Round 1
// baseline (316.244 us; speedup 1.0000x reference)
//
#include <hip/hip_runtime.h>
#include <hip/hip_bf16.h>

typedef __bf16 bf16x8 __attribute__((ext_vector_type(8)));
typedef float f32x4 __attribute__((ext_vector_type(4)));
typedef unsigned short u16;
typedef u16 u16x8 __attribute__((ext_vector_type(8)));

__device__ __forceinline__ u16 f2bf(float f) {
  union { float f; unsigned u; } v; v.f = f;
  unsigned r = v.u + 0x7fffu + ((v.u >> 16) & 1u);
  return (u16)(r >> 16);
}

// ---------------- cast x: f32 -> bf16, 8 elems/thread ----------------
__global__ __launch_bounds__(256) void cast_x_k(const float* __restrict__ x,
                                                u16* __restrict__ xb, int n8) {
  int id = blockIdx.x * 256 + threadIdx.x;
  if (id >= n8) return;
  const float4* p = (const float4*)(x + (size_t)id * 8);
  float4 a = p[0], b = p[1];
  u16x8 o;
  o[0] = f2bf(a.x); o[1] = f2bf(a.y); o[2] = f2bf(a.z); o[3] = f2bf(a.w);
  o[4] = f2bf(b.x); o[5] = f2bf(b.y); o[6] = f2bf(b.z); o[7] = f2bf(b.w);
  *(u16x8*)(xb + (size_t)id * 8) = o;
}

// ------------- transpose-cast W [R][Cc] f32 -> Wt [Cc][R] bf16 -------------
__global__ __launch_bounds__(256) void tcast_k(const float* __restrict__ W,
                                               u16* __restrict__ Wt, int R, int Cc) {
  __shared__ float tile[32][33];
  int bx = blockIdx.x * 32, by = blockIdx.y * 32;
  int tx = threadIdx.x & 31, ty = threadIdx.x >> 5; // ty: 0..7
#pragma unroll
  for (int j = 0; j < 4; j++)
    tile[ty + j * 8][tx] = W[(size_t)(by + ty + j * 8) * Cc + bx + tx];
  __syncthreads();
#pragma unroll
  for (int j = 0; j < 4; j++)
    Wt[(size_t)(bx + ty + j * 8) * R + by + tx] = f2bf(tile[tx][ty + j * 8]);
}

// ---------------- GEMM: C[M][N] = A[M][K](bf16) * Bt[N][K](bf16) + bias ----------------
// 128x128 tile, 4 waves, BK=64, XOR-swizzled LDS (row stride 128B would be 16-way conflict).
__global__ __launch_bounds__(256) void gemm_bt_k(const u16* __restrict__ A,
                                                 const u16* __restrict__ Bt,
                                                 const float* __restrict__ bias,
                                                 float* __restrict__ C,
                                                 int M, int N, int K) {
  __shared__ u16 As[128 * 64];
  __shared__ u16 Bs[128 * 64];
  int tid = threadIdx.x;
  int m0 = blockIdx.y * 128, n0 = blockIdx.x * 128;
  int wave = tid >> 6, lane = tid & 63;
  int wm = (wave & 1) * 64, wn = (wave >> 1) * 64;
  int lrow = lane & 15, lk = (lane >> 4) * 8;
  int srow = tid >> 3;          // 0..31
  int scol = (tid & 7) * 8;     // 0..56

  f32x4 acc[4][4] = {};

  for (int k0 = 0; k0 < K; k0 += 64) {
#pragma unroll
    for (int p = 0; p < 4; p++) {
      int row = srow + p * 32;
      int wb = (row * 128 + scol * 2) ^ ((row & 7) << 4);
      bf16x8 av = *(const bf16x8*)(A + (size_t)(m0 + row) * K + k0 + scol);
      *(bf16x8*)((char*)As + wb) = av;
      bf16x8 bv = *(const bf16x8*)(Bt + (size_t)(n0 + row) * K + k0 + scol);
      *(bf16x8*)((char*)Bs + wb) = bv;
    }
    __syncthreads();
#pragma unroll
    for (int kk = 0; kk < 2; kk++) {
      bf16x8 af[4], bfr[4];
#pragma unroll
      for (int i = 0; i < 4; i++) {
        int arow = wm + i * 16 + lrow;
        int ab = (arow * 128 + (kk * 32 + lk) * 2) ^ ((arow & 7) << 4);
        af[i] = *(const bf16x8*)((const char*)As + ab);
        int brow = wn + i * 16 + lrow;
        int bb = (brow * 128 + (kk * 32 + lk) * 2) ^ ((brow & 7) << 4);
        bfr[i] = *(const bf16x8*)((const char*)Bs + bb);
      }
#pragma unroll
      for (int i = 0; i < 4; i++)
#pragma unroll
        for (int j = 0; j < 4; j++)
          acc[i][j] = __builtin_amdgcn_mfma_f32_16x16x32_bf16(af[i], bfr[j], acc[i][j], 0, 0, 0);
    }
    __syncthreads();
  }
  int rg = lane >> 4;
#pragma unroll
  for (int i = 0; i < 4; i++) {
#pragma unroll
    for (int j = 0; j < 4; j++) {
      int col = n0 + wn + j * 16 + lrow;
      float bz = bias ? bias[col] : 0.f;
#pragma unroll
      for (int r = 0; r < 4; r++) {
        int row = m0 + wm + i * 16 + rg * 4 + r;
        C[(size_t)row * N + col] = acc[i][j][r] + bz;
      }
    }
  }
}

// ---------------- RoPE on q,k; pack to (B,H,T,dk) bf16 ----------------
// one thread per (b,t,h,pair)
__global__ __launch_bounds__(256) void rope_qk_k(const float* __restrict__ qkv,
                                                 u16* __restrict__ qb,
                                                 u16* __restrict__ kb) {
  int id = blockIdx.x * 256 + threadIdx.x;
  int i = id & 31;
  int h = (id >> 5) & 15;
  int t = (id >> 9) & 2047;
  int b = id >> 20;
  size_t row = (size_t)b * 2048 + t;
  const float* base = qkv + row * 3072 + h * 64 + 2 * i;
  float2 qp = *(const float2*)(base);
  float2 kp = *(const float2*)(base + 1024);
  // freq = 10000^(-2i/64) = 2^(i * -2*log2(10000)/64)
  float freq = exp2f((float)i * -0.41524101186092029f);
  float ang = (float)t * freq;
  float sv, cv;
  sincosf(ang, &sv, &cv);  // precise path: |ang| up to ~2047 rad
  size_t obase = (((size_t)(b * 16 + h) * 2048) + t) * 64 + 2 * i;
  ushort2 qo, ko;
  qo.x = f2bf(qp.x * cv - qp.y * sv); qo.y = f2bf(qp.x * sv + qp.y * cv);
  ko.x = f2bf(kp.x * cv - kp.y * sv); ko.y = f2bf(kp.x * sv + kp.y * cv);
  *(ushort2*)(qb + obase) = qo;
  *(ushort2*)(kb + obase) = ko;
}

// ---------------- V pack transposed: (B,H,dk,T) bf16 ----------------
__global__ __launch_bounds__(256) void v_trans_k(const float* __restrict__ qkv,
                                                 u16* __restrict__ vt) {
  int bh = blockIdx.x;
  int t0 = blockIdx.y * 64;
  int tx = threadIdx.x & 63, ty = threadIdx.x >> 6; // ty: 0..3
  int b = bh >> 4, h = bh & 15;
  int t = t0 + tx;
  const float* src = qkv + ((size_t)(b * 2048 + t)) * 3072 + 2048 + h * 64 + ty * 16;
  u16* dst = vt + (size_t)bh * 64 * 2048;
#pragma unroll
  for (int j = 0; j < 16; j++) {
    dst[(size_t)(ty * 16 + j) * 2048 + t] = f2bf(src[j]);
  }
}

// ---------------- flash attention, causal, 4 waves x 16 q-rows ----------------
__global__ __launch_bounds__(256) void attn_k(const u16* __restrict__ Q,
                                              const u16* __restrict__ Kb,
                                              const u16* __restrict__ Vt,
                                              u16* __restrict__ Os, int T) {
  __shared__ u16 P[4][16][88];  // per-wave P buffer; stride 88 -> 16B aligned, 2-way banks
  int bh = blockIdx.y;
  int q0 = blockIdx.x * 64;
  int tid = threadIdx.x, wave = tid >> 6, lane = tid & 63;
  int lrow = lane & 15, lg = lane >> 4, lk = lg * 8;
  int qr0 = q0 + wave * 16;
  const u16* Qp = Q + (size_t)bh * T * 64;
  const u16* Kp = Kb + (size_t)bh * T * 64;
  const u16* Vp = Vt + (size_t)bh * 64 * T;

  bf16x8 aq[2];
#pragma unroll
  for (int kk = 0; kk < 2; kk++)
    aq[kk] = *(const bf16x8*)(Qp + (size_t)(qr0 + lrow) * 64 + kk * 32 + lk);

  f32x4 acc[4] = {};
  float mr[4], lr[4];
#pragma unroll
  for (int r = 0; r < 4; r++) { mr[r] = -1e30f; lr[r] = 0.f; }

  int ntiles = q0 / 64 + 1;
  for (int kt = 0; kt < ntiles; kt++) {
    int kv0 = kt * 64;
    f32x4 S[4] = {};
#pragma unroll
    for (int kk = 0; kk < 2; kk++) {
#pragma unroll
      for (int nb = 0; nb < 4; nb++) {
        bf16x8 bk = *(const bf16x8*)(Kp + (size_t)(kv0 + nb * 16 + lrow) * 64 + kk * 32 + lk);
        S[nb] = __builtin_amdgcn_mfma_f32_16x16x32_bf16(aq[kk], bk, S[nb], 0, 0, 0);
      }
    }
    // scale + causal mask + row stats
    float pv[4][4], tmax[4];
#pragma unroll
    for (int r = 0; r < 4; r++) tmax[r] = -1e30f;
#pragma unroll
    for (int nb = 0; nb < 4; nb++) {
      int key = kv0 + nb * 16 + lrow;
#pragma unroll
      for (int r = 0; r < 4; r++) {
        int qi = qr0 + lg * 4 + r;
        float s = S[nb][r] * 0.125f;
        if (key > qi) s = -1e30f;
        pv[nb][r] = s;
        tmax[r] = fmaxf(tmax[r], s);
      }
    }
#pragma unroll
    for (int m = 1; m < 16; m <<= 1)
#pragma unroll
      for (int r = 0; r < 4; r++) tmax[r] = fmaxf(tmax[r], __shfl_xor(tmax[r], m));
    float corr[4], tsum[4];
#pragma unroll
    for (int r = 0; r < 4; r++) {
      float mn = fmaxf(mr[r], tmax[r]);
      corr[r] = __expf(mr[r] - mn);
      mr[r] = mn;
      tsum[r] = 0.f;
    }
#pragma unroll
    for (int nb = 0; nb < 4; nb++)
#pragma unroll
      for (int r = 0; r < 4; r++) {
        float p = __expf(pv[nb][r] - mr[r]);
        pv[nb][r] = p;
        tsum[r] += p;
      }
#pragma unroll
    for (int m = 1; m < 16; m <<= 1)
#pragma unroll
      for (int r = 0; r < 4; r++) tsum[r] += __shfl_xor(tsum[r], m);
#pragma unroll
    for (int r = 0; r < 4; r++) lr[r] = lr[r] * corr[r] + tsum[r];
    // rescale O
#pragma unroll
    for (int nb = 0; nb < 4; nb++)
#pragma unroll
      for (int r = 0; r < 4; r++) acc[nb][r] *= corr[r];
    // P -> LDS (bf16)
#pragma unroll
    for (int nb = 0; nb < 4; nb++)
#pragma unroll
      for (int r = 0; r < 4; r++)
        P[wave][lg * 4 + r][nb * 16 + lrow] = f2bf(pv[nb][r]);
    // PV
#pragma unroll
    for (int kk = 0; kk < 2; kk++) {
      bf16x8 ap = *(const bf16x8*)(&P[wave][lrow][kk * 32 + lk]);
#pragma unroll
      for (int nb = 0; nb < 4; nb++) {
        bf16x8 bv = *(const bf16x8*)(Vp + (size_t)(nb * 16 + lrow) * T + kv0 + kk * 32 + lk);
        acc[nb] = __builtin_amdgcn_mfma_f32_16x16x32_bf16(ap, bv, acc[nb], 0, 0, 0);
      }
    }
  }
  // epilogue: O/l -> scores (B*T, C) bf16, fused head re-interleave
  int b = bh >> 4, h = bh & 15;
#pragma unroll
  for (int r = 0; r < 4; r++) {
    float inv = 1.f / lr[r];
    int row = qr0 + lg * 4 + r;
#pragma unroll
    for (int nb = 0; nb < 4; nb++)
      Os[((size_t)(b * T + row)) * 1024 + h * 64 + nb * 16 + lrow] = f2bf(acc[nb][r] * inv);
  }
}

extern "C" void kernel_launch(void* const* d_in, const int* in_sizes, int n_in,
                              void* d_out, int out_size, void* d_ws, size_t ws_size,
                              hipStream_t stream) {
  const float* x      = (const float*)d_in[0];
  const float* W_qkv  = (const float*)d_in[1];
  const float* b_qkv  = (const float*)d_in[2];
  const float* W_proj = (const float*)d_in[3];
  const float* b_proj = (const float*)d_in[4];
  float* out = (float*)d_out;

  const int B = 2, T = 2048, C = 1024;
  const int M = B * T;  // 4096

  char* ws = (char*)d_ws;
  u16* xb     = (u16*)(ws);                       // 8 MB
  u16* wqkvt  = (u16*)(ws + (8ull << 20));        // 6 MB
  u16* wprojt = (u16*)(ws + (14ull << 20));       // 2 MB
  u16* qb     = (u16*)(ws + (16ull << 20));       // 8 MB
  u16* kb     = (u16*)(ws + (24ull << 20));       // 8 MB
  u16* vt     = (u16*)(ws + (32ull << 20));       // 8 MB
  u16* sc     = (u16*)(ws + (40ull << 20));       // 8 MB
  float* qkv  = (float*)(ws + (48ull << 20));     // 48 MB

  // 1. casts
  cast_x_k<<<(M * C / 8 + 255) / 256, 256, 0, stream>>>(x, xb, M * C / 8);
  tcast_k<<<dim3(3 * C / 32, C / 32), 256, 0, stream>>>(W_qkv, wqkvt, C, 3 * C);
  tcast_k<<<dim3(C / 32, C / 32), 256, 0, stream>>>(W_proj, wprojt, C, C);
  // 2. qkv = x @ W_qkv + b  (fp32 out)
  gemm_bt_k<<<dim3(3 * C / 128, M / 128), 256, 0, stream>>>(xb, wqkvt, b_qkv, qkv, M, 3 * C, C);
  // 3. rope + pack
  rope_qk_k<<<(B * T * 16 * 32) / 256, 256, 0, stream>>>(qkv, qb, kb);
  v_trans_k<<<dim3(B * 16, T / 64), 256, 0, stream>>>(qkv, vt);
  // 4. flash attention
  attn_k<<<dim3(T / 64, B * 16), 256, 0, stream>>>(qb, kb, vt, sc, T);
  // 5. out = scores @ W_proj + b
  gemm_bt_k<<<dim3(C / 128, M / 128), 256, 0, stream>>>(sc, wprojt, b_proj, out, M, C, C);
}

// Round 2
// 157.167 us; speedup vs baseline: 2.0122x; 2.0122x over previous
//
#include <hip/hip_runtime.h>
#include <hip/hip_bf16.h>

typedef __bf16 bf16x8 __attribute__((ext_vector_type(8)));
typedef float f32x4 __attribute__((ext_vector_type(4)));
typedef float f32x16 __attribute__((ext_vector_type(16)));
typedef unsigned short u16;
typedef u16 u16x8 __attribute__((ext_vector_type(8)));

__device__ __forceinline__ u16 f2bf(float f) {
  union { float f; unsigned u; } v; v.f = f;
  unsigned r = v.u + 0x7fffu + ((v.u >> 16) & 1u);
  return (u16)(r >> 16);
}
__device__ __forceinline__ unsigned pk2(float a, float b) {
  return (unsigned)f2bf(a) | ((unsigned)f2bf(b) << 16);
}
// async global->LDS, 16B per lane, dest = uniform base + lane*16
__device__ __forceinline__ void gload16(const void* g, void* l) {
  __builtin_amdgcn_global_load_lds(
      (__attribute__((address_space(1))) void*)(void*)g,
      (__attribute__((address_space(3))) void*)l, 16, 0, 0);
}

union U8 { bf16x8 v; unsigned u[4]; };

// ---------------- cast x: f32 -> bf16, 8 elems/thread ----------------
__global__ __launch_bounds__(256) void cast_x_k(const float* __restrict__ x,
                                                u16* __restrict__ xb, int n8) {
  int id = blockIdx.x * 256 + threadIdx.x;
  if (id >= n8) return;
  const float4* p = (const float4*)(x + (size_t)id * 8);
  float4 a = p[0], b = p[1];
  u16x8 o;
  o[0] = f2bf(a.x); o[1] = f2bf(a.y); o[2] = f2bf(a.z); o[3] = f2bf(a.w);
  o[4] = f2bf(b.x); o[5] = f2bf(b.y); o[6] = f2bf(b.z); o[7] = f2bf(b.w);
  *(u16x8*)(xb + (size_t)id * 8) = o;
}

// ------------- transpose-cast W [R][Cc] f32 -> Wt [Cc][R] bf16 -------------
__global__ __launch_bounds__(256) void tcast_k(const float* __restrict__ W,
                                               u16* __restrict__ Wt, int R, int Cc) {
  __shared__ float tile[32][33];
  int bx = blockIdx.x * 32, by = blockIdx.y * 32;
  int tx = threadIdx.x & 31, ty = threadIdx.x >> 5;
#pragma unroll
  for (int j = 0; j < 4; j++)
    tile[ty + j * 8][tx] = W[(size_t)(by + ty + j * 8) * Cc + bx + tx];
  __syncthreads();
#pragma unroll
  for (int j = 0; j < 4; j++)
    Wt[(size_t)(bx + ty + j * 8) * R + by + tx] = f2bf(tile[tx][ty + j * 8]);
}

// ---------------- GEMM: C[M][N] = A[M][K](bf16) * Bt[N][K](bf16) + bias ----------------
// 128x128 tile, 4 waves, BK=64. global_load_lds width-16 staging with
// pre-swizzled source (linear LDS dest + XOR (row&7)<<4 read swizzle).
__global__ __launch_bounds__(256) void gemm_bt_k(const u16* __restrict__ A,
                                                 const u16* __restrict__ Bt,
                                                 const float* __restrict__ bias,
                                                 float* __restrict__ C,
                                                 int M, int N, int K) {
  __shared__ u16 As[128 * 64];
  __shared__ u16 Bs[128 * 64];
  int tid = threadIdx.x;
  int m0 = blockIdx.y * 128, n0 = blockIdx.x * 128;
  int wave = tid >> 6, lane = tid & 63;
  int wm = (wave & 1) * 64, wn = (wave >> 1) * 64;
  int lrow = lane & 15, lk = (lane >> 4) * 8;
  int rr = lane >> 3, cb = (lane & 7) * 16;

  f32x4 acc[4][4] = {};

  for (int k0 = 0; k0 < K; k0 += 64) {
#pragma unroll
    for (int i = 0; i < 4; i++) {
      int row = wave * 32 + i * 8 + rr;
      int cc = (cb ^ ((row & 7) << 4)) >> 1;
      gload16(A + (size_t)(m0 + row) * K + k0 + cc, &As[(wave * 32 + i * 8) * 64]);
      gload16(Bt + (size_t)(n0 + row) * K + k0 + cc, &Bs[(wave * 32 + i * 8) * 64]);
    }
    __syncthreads();
#pragma unroll
    for (int kk = 0; kk < 2; kk++) {
      bf16x8 af[4], bfr[4];
#pragma unroll
      for (int i = 0; i < 4; i++) {
        int arow = wm + i * 16 + lrow;
        int ab = (arow * 128 + (kk * 32 + lk) * 2) ^ ((arow & 7) << 4);
        af[i] = *(const bf16x8*)((const char*)As + ab);
        int brow = wn + i * 16 + lrow;
        int bb = (brow * 128 + (kk * 32 + lk) * 2) ^ ((brow & 7) << 4);
        bfr[i] = *(const bf16x8*)((const char*)Bs + bb);
      }
#pragma unroll
      for (int i = 0; i < 4; i++)
#pragma unroll
        for (int j = 0; j < 4; j++)
          acc[i][j] = __builtin_amdgcn_mfma_f32_16x16x32_bf16(af[i], bfr[j], acc[i][j], 0, 0, 0);
    }
    __syncthreads();
  }
  int rg = lane >> 4;
#pragma unroll
  for (int i = 0; i < 4; i++) {
#pragma unroll
    for (int j = 0; j < 4; j++) {
      int col = n0 + wn + j * 16 + lrow;
      float bz = bias ? bias[col] : 0.f;
#pragma unroll
      for (int r = 0; r < 4; r++) {
        int row = m0 + wm + i * 16 + rg * 4 + r;
        C[(size_t)row * N + col] = acc[i][j][r] + bz;
      }
    }
  }
}

// ---------------- RoPE on q,k; pack to (B,H,T,dk) bf16 ----------------
__global__ __launch_bounds__(256) void rope_qk_k(const float* __restrict__ qkv,
                                                 u16* __restrict__ qb,
                                                 u16* __restrict__ kb) {
  int id = blockIdx.x * 256 + threadIdx.x;
  int i = id & 31;
  int h = (id >> 5) & 15;
  int t = (id >> 9) & 2047;
  int b = id >> 20;
  size_t row = (size_t)b * 2048 + t;
  const float* base = qkv + row * 3072 + h * 64 + 2 * i;
  float2 qp = *(const float2*)(base);
  float2 kp = *(const float2*)(base + 1024);
  float freq = exp2f((float)i * -0.41524101186092029f);
  float ang = (float)t * freq;
  float sv, cv;
  sincosf(ang, &sv, &cv);
  size_t obase = (((size_t)(b * 16 + h) * 2048) + t) * 64 + 2 * i;
  ushort2 qo, ko;
  qo.x = f2bf(qp.x * cv - qp.y * sv); qo.y = f2bf(qp.x * sv + qp.y * cv);
  ko.x = f2bf(kp.x * cv - kp.y * sv); ko.y = f2bf(kp.x * sv + kp.y * cv);
  *(ushort2*)(qb + obase) = qo;
  *(ushort2*)(kb + obase) = ko;
}

// ---------------- V pack transposed: (B,H,dk,T) bf16 ----------------
__global__ __launch_bounds__(256) void v_trans_k(const float* __restrict__ qkv,
                                                 u16* __restrict__ vt) {
  int bh = blockIdx.x;
  int t0 = blockIdx.y * 64;
  int tx = threadIdx.x & 63, ty = threadIdx.x >> 6;
  int b = bh >> 4, h = bh & 15;
  int t = t0 + tx;
  const float* src = qkv + ((size_t)(b * 2048 + t)) * 3072 + 2048 + h * 64 + ty * 16;
  u16* dst = vt + (size_t)bh * 64 * 2048;
#pragma unroll
  for (int j = 0; j < 16; j++) {
    dst[(size_t)(ty * 16 + j) * 2048 + t] = f2bf(src[j]);
  }
}

// ---------------- flash attention v2: swapped-QK 32x32 MFMA ----------------
// 4 waves x 32 q-rows = 128-row q-block; KVBLK=64; K,V in double-buffered LDS
// (global_load_lds, XOR-swizzled); lane-local softmax via S^T layout.
#define ATTN_STAGE(BUF, KV0)                                                     \
  {                                                                              \
    _Pragma("unroll") for (int i_ = 0; i_ < 2; i_++) {                           \
      int rr_ = wave * 16 + i_ * 8 + (lane >> 3);                                \
      int cc_ = (((lane & 7) * 16) ^ ((rr_ & 7) << 4)) >> 1;                     \
      gload16(Kp + (size_t)((KV0) + rr_) * 64 + cc_,                             \
              &Kls[BUF][(wave * 16 + i_ * 8) * 64]);                             \
      gload16(Vp + (size_t)rr_ * 2048 + (KV0) + cc_,                             \
              &Vls[BUF][(wave * 16 + i_ * 8) * 64]);                             \
    }                                                                            \
  }

__global__ __launch_bounds__(256) void attn_k(const u16* __restrict__ Q,
                                              const u16* __restrict__ Kb,
                                              const u16* __restrict__ Vt,
                                              u16* __restrict__ Os) {
  __shared__ u16 Kls[2][64 * 64];
  __shared__ u16 Vls[2][64 * 64];
  const int T = 2048;
  int g = blockIdx.x;
  int bh = g & 31;
  int slot = g >> 5;                                  // 0..15
  int qt = (slot < 8) ? (2 * slot) : (31 - 2 * slot); // heavy/light pairing
  int q0 = qt * 128;
  int wave = threadIdx.x >> 6, lane = threadIdx.x & 63;
  int ql = lane & 31, hi = lane >> 5;
  int qw0 = q0 + wave * 32;
  const u16* Qp = Q + (size_t)bh * T * 64;
  const u16* Kp = Kb + (size_t)bh * T * 64;
  const u16* Vp = Vt + (size_t)bh * 64 * T;

  // Q fragments (B operand of QK): col q = lane&31, dd = ds*16 + hi*8 + i
  bf16x8 qf[4];
#pragma unroll
  for (int ds = 0; ds < 4; ds++)
    qf[ds] = *(const bf16x8*)(Qp + (size_t)(qw0 + ql) * 64 + ds * 16 + hi * 8);

  f32x16 ot0 = {}, ot1 = {};  // O^T: col q = lane&31, rows d (+0 / +32)
  float m = -1e30f, l = 0.f;
  int qg = qw0 + ql;
  int swzk = (ql & 7) << 4;

  int nt = q0 / 64 + 2;
  ATTN_STAGE(0, 0)
  __syncthreads();

  for (int t = 0; t < nt; ++t) {
    int bb = t & 1;
    int kv0 = t * 64;
    if (t + 1 < nt) ATTN_STAGE((t + 1) & 1, (t + 1) * 64)

    if (kv0 <= qw0 + 31) {
      const char* Kb_ = (const char*)&Kls[bb][0];
      const char* Vb_ = (const char*)&Vls[bb][0];
      // ---- QK^T (swapped): S^T[k][q] ----
      f32x16 st0 = {}, st1 = {};
#pragma unroll
      for (int ds = 0; ds < 4; ds++) {
        int c = ds * 32 + hi * 16;
        bf16x8 k0 = *(const bf16x8*)(Kb_ + ql * 128 + (c ^ swzk));
        bf16x8 k1 = *(const bf16x8*)(Kb_ + (32 + ql) * 128 + (c ^ swzk));
        st0 = __builtin_amdgcn_mfma_f32_32x32x16_bf16(k0, qf[ds], st0, 0, 0, 0);
        st1 = __builtin_amdgcn_mfma_f32_32x32x16_bf16(k1, qf[ds], st1, 0, 0, 0);
      }
      // ---- scale + causal mask ----
      if (kv0 + 31 > qw0) {
#pragma unroll
        for (int r = 0; r < 16; r++) {
          int k = kv0 + ((r & 3) + 8 * (r >> 2) + 4 * hi);
          st0[r] = (k > qg) ? -1e30f : st0[r] * 0.125f;
        }
      } else {
#pragma unroll
        for (int r = 0; r < 16; r++) st0[r] *= 0.125f;
      }
      if (kv0 + 63 > qw0) {
#pragma unroll
        for (int r = 0; r < 16; r++) {
          int k = kv0 + 32 + ((r & 3) + 8 * (r >> 2) + 4 * hi);
          st1[r] = (k > qg) ? -1e30f : st1[r] * 0.125f;
        }
      } else {
#pragma unroll
        for (int r = 0; r < 16; r++) st1[r] *= 0.125f;
      }
      // ---- lane-local softmax (one cross-lane swap) ----
      float mx[8];
#pragma unroll
      for (int r = 0; r < 8; r++)
        mx[r] = fmaxf(fmaxf(st0[r], st0[r + 8]), fmaxf(st1[r], st1[r + 8]));
      mx[0] = fmaxf(mx[0], mx[4]); mx[1] = fmaxf(mx[1], mx[5]);
      mx[2] = fmaxf(mx[2], mx[6]); mx[3] = fmaxf(mx[3], mx[7]);
      float tmax = fmaxf(fmaxf(mx[0], mx[1]), fmaxf(mx[2], mx[3]));
      tmax = fmaxf(tmax, __shfl_xor(tmax, 32));
      float mn = fmaxf(m, tmax);
      float corr = __expf(m - mn);
      m = mn;
      float ps0 = 0.f, ps1 = 0.f, ps2 = 0.f, ps3 = 0.f;
#pragma unroll
      for (int r = 0; r < 8; r++) {
        float a0 = __expf(st0[r] - mn);      st0[r] = a0;      ps0 += a0;
        float a1 = __expf(st0[r + 8] - mn);  st0[r + 8] = a1;  ps1 += a1;
        float a2 = __expf(st1[r] - mn);      st1[r] = a2;      ps2 += a2;
        float a3 = __expf(st1[r + 8] - mn);  st1[r + 8] = a3;  ps3 += a3;
      }
      float ts = (ps0 + ps1) + (ps2 + ps3);
      ts += __shfl_xor(ts, 32);
      l = l * corr + ts;
#pragma unroll
      for (int r = 0; r < 16; r++) { ot0[r] *= corr; ot1[r] *= corr; }
      // ---- pack P^T -> bf16 B-fragments (one shfl_xor(32) per word) ----
      unsigned w0_[8], w1_[8], x0_[8], x1_[8];
#pragma unroll
      for (int j = 0; j < 8; j++) {
        w0_[j] = pk2(st0[2 * j], st0[2 * j + 1]);
        w1_[j] = pk2(st1[2 * j], st1[2 * j + 1]);
      }
#pragma unroll
      for (int j = 0; j < 8; j++) {
        x0_[j] = (unsigned)__shfl_xor((int)w0_[j], 32);
        x1_[j] = (unsigned)__shfl_xor((int)w1_[j], 32);
      }
      U8 pf00, pf01, pf10, pf11;
      pf00.u[0] = hi ? x0_[2] : w0_[0]; pf00.u[1] = hi ? x0_[3] : w0_[1];
      pf00.u[2] = hi ? w0_[2] : x0_[0]; pf00.u[3] = hi ? w0_[3] : x0_[1];
      pf01.u[0] = hi ? x0_[6] : w0_[4]; pf01.u[1] = hi ? x0_[7] : w0_[5];
      pf01.u[2] = hi ? w0_[6] : x0_[4]; pf01.u[3] = hi ? w0_[7] : x0_[5];
      pf10.u[0] = hi ? x1_[2] : w1_[0]; pf10.u[1] = hi ? x1_[3] : w1_[1];
      pf10.u[2] = hi ? w1_[2] : x1_[0]; pf10.u[3] = hi ? w1_[3] : x1_[1];
      pf11.u[0] = hi ? x1_[6] : w1_[4]; pf11.u[1] = hi ? x1_[7] : w1_[5];
      pf11.u[2] = hi ? w1_[6] : x1_[4]; pf11.u[3] = hi ? w1_[7] : x1_[5];
      // ---- PV: O^T[d][q] += V^T[d][k] * P^T[k][q] ----
      {
        const char* vb = Vb_ + ql * 128;
        int vs = swzk;
        ot0 = __builtin_amdgcn_mfma_f32_32x32x16_bf16(*(const bf16x8*)(vb + ((hi * 16) ^ vs)), pf00.v, ot0, 0, 0, 0);
        ot0 = __builtin_amdgcn_mfma_f32_32x32x16_bf16(*(const bf16x8*)(vb + ((32 + hi * 16) ^ vs)), pf01.v, ot0, 0, 0, 0);
        ot0 = __builtin_amdgcn_mfma_f32_32x32x16_bf16(*(const bf16x8*)(vb + ((64 + hi * 16) ^ vs)), pf10.v, ot0, 0, 0, 0);
        ot0 = __builtin_amdgcn_mfma_f32_32x32x16_bf16(*(const bf16x8*)(vb + ((96 + hi * 16) ^ vs)), pf11.v, ot0, 0, 0, 0);
      }
      {
        const char* vb = Vb_ + (32 + ql) * 128;
        int vs = swzk;
        ot1 = __builtin_amdgcn_mfma_f32_32x32x16_bf16(*(const bf16x8*)(vb + ((hi * 16) ^ vs)), pf00.v, ot1, 0, 0, 0);
        ot1 = __builtin_amdgcn_mfma_f32_32x32x16_bf16(*(const bf16x8*)(vb + ((32 + hi * 16) ^ vs)), pf01.v, ot1, 0, 0, 0);
        ot1 = __builtin_amdgcn_mfma_f32_32x32x16_bf16(*(const bf16x8*)(vb + ((64 + hi * 16) ^ vs)), pf10.v, ot1, 0, 0, 0);
        ot1 = __builtin_amdgcn_mfma_f32_32x32x16_bf16(*(const bf16x8*)(vb + ((96 + hi * 16) ^ vs)), pf11.v, ot1, 0, 0, 0);
      }
    }
    __syncthreads();
  }

  // ---- epilogue: O = O^T/l, fused head re-interleave into (B*T, C) bf16 ----
  float inv = 1.f / l;
  int b = bh >> 4, h = bh & 15;
  u16* orow = Os + ((size_t)(b * T + qg)) * 1024 + h * 64;
#pragma unroll
  for (int j = 0; j < 4; j++) {
    ushort4 o;
    o.x = f2bf(ot0[4 * j + 0] * inv); o.y = f2bf(ot0[4 * j + 1] * inv);
    o.z = f2bf(ot0[4 * j + 2] * inv); o.w = f2bf(ot0[4 * j + 3] * inv);
    *(ushort4*)(orow + 8 * j + 4 * hi) = o;
    ushort4 p;
    p.x = f2bf(ot1[4 * j + 0] * inv); p.y = f2bf(ot1[4 * j + 1] * inv);
    p.z = f2bf(ot1[4 * j + 2] * inv); p.w = f2bf(ot1[4 * j + 3] * inv);
    *(ushort4*)(orow + 32 + 8 * j + 4 * hi) = p;
  }
}

extern "C" void kernel_launch(void* const* d_in, const int* in_sizes, int n_in,
                              void* d_out, int out_size, void* d_ws, size_t ws_size,
                              hipStream_t stream) {
  const float* x      = (const float*)d_in[0];
  const float* W_qkv  = (const float*)d_in[1];
  const float* b_qkv  = (const float*)d_in[2];
  const float* W_proj = (const float*)d_in[3];
  const float* b_proj = (const float*)d_in[4];
  float* out = (float*)d_out;

  const int B = 2, T = 2048, C = 1024;
  const int M = B * T;  // 4096

  char* ws = (char*)d_ws;
  u16* xb     = (u16*)(ws);                       // 8 MB
  u16* wqkvt  = (u16*)(ws + (8ull << 20));        // 6 MB
  u16* wprojt = (u16*)(ws + (14ull << 20));       // 2 MB
  u16* qb     = (u16*)(ws + (16ull << 20));       // 8 MB
  u16* kb     = (u16*)(ws + (24ull << 20));       // 8 MB
  u16* vt     = (u16*)(ws + (32ull << 20));       // 8 MB
  u16* sc     = (u16*)(ws + (40ull << 20));       // 8 MB
  float* qkv  = (float*)(ws + (48ull << 20));     // 48 MB

  cast_x_k<<<(M * C / 8 + 255) / 256, 256, 0, stream>>>(x, xb, M * C / 8);
  tcast_k<<<dim3(3 * C / 32, C / 32), 256, 0, stream>>>(W_qkv, wqkvt, C, 3 * C);
  tcast_k<<<dim3(C / 32, C / 32), 256, 0, stream>>>(W_proj, wprojt, C, C);
  gemm_bt_k<<<dim3(3 * C / 128, M / 128), 256, 0, stream>>>(xb, wqkvt, b_qkv, qkv, M, 3 * C, C);
  rope_qk_k<<<(B * T * 16 * 32) / 256, 256, 0, stream>>>(qkv, qb, kb);
  v_trans_k<<<dim3(B * 16, T / 64), 256, 0, stream>>>(qkv, vt);
  attn_k<<<512, 256, 0, stream>>>(qb, kb, vt, sc);
  gemm_bt_k<<<dim3(C / 128, M / 128), 256, 0, stream>>>(sc, wprojt, b_proj, out, M, C, C);
}

// Round 3
// 146.947 us; speedup vs baseline: 2.1521x; 1.0695x over previous
//
#include <hip/hip_runtime.h>
#include <hip/hip_bf16.h>

typedef __bf16 bf16x8 __attribute__((ext_vector_type(8)));
typedef float f32x4 __attribute__((ext_vector_type(4)));
typedef float f32x16 __attribute__((ext_vector_type(16)));
typedef unsigned short u16;
typedef u16 u16x8 __attribute__((ext_vector_type(8)));

__device__ __forceinline__ u16 f2bf(float f) {
  union { float f; unsigned u; } v; v.f = f;
  unsigned r = v.u + 0x7fffu + ((v.u >> 16) & 1u);
  return (u16)(r >> 16);
}
__device__ __forceinline__ float bf2f(u16 u) {
  union { unsigned u; float f; } v; v.u = (unsigned)u << 16; return v.f;
}
__device__ __forceinline__ unsigned cvtpk(float a, float b) {
  unsigned r;
  asm("v_cvt_pk_bf16_f32 %0, %1, %2" : "=v"(r) : "v"(a), "v"(b));
  return r;
}
__device__ __forceinline__ float exp2_(float x) {
  float r;
  asm("v_exp_f32 %0, %1" : "=v"(r) : "v"(x));
  return r;
}
// async global->LDS, 16B per lane, dest = wave-uniform base + lane*16
__device__ __forceinline__ void gload16(const void* g, void* l) {
  __builtin_amdgcn_global_load_lds(
      (__attribute__((address_space(1))) void*)(void*)g,
      (__attribute__((address_space(3))) void*)l, 16, 0, 0);
}

union U8 { bf16x8 v; unsigned u[4]; };

// ---------------- cast x: f32 -> bf16, 8 elems/thread ----------------
__global__ __launch_bounds__(256) void cast_x_k(const float* __restrict__ x,
                                                u16* __restrict__ xb, int n8) {
  int id = blockIdx.x * 256 + threadIdx.x;
  if (id >= n8) return;
  const float4* p = (const float4*)(x + (size_t)id * 8);
  float4 a = p[0], b = p[1];
  u16x8 o;
  o[0] = f2bf(a.x); o[1] = f2bf(a.y); o[2] = f2bf(a.z); o[3] = f2bf(a.w);
  o[4] = f2bf(b.x); o[5] = f2bf(b.y); o[6] = f2bf(b.z); o[7] = f2bf(b.w);
  *(u16x8*)(xb + (size_t)id * 8) = o;
}

// ------------- transpose-cast W [R][Cc] f32 -> Wt [Cc][R] bf16 -------------
__global__ __launch_bounds__(256) void tcast_k(const float* __restrict__ W,
                                               u16* __restrict__ Wt, int R, int Cc) {
  __shared__ float tile[32][33];
  int bx = blockIdx.x * 32, by = blockIdx.y * 32;
  int tx = threadIdx.x & 31, ty = threadIdx.x >> 5;
#pragma unroll
  for (int j = 0; j < 4; j++)
    tile[ty + j * 8][tx] = W[(size_t)(by + ty + j * 8) * Cc + bx + tx];
  __syncthreads();
#pragma unroll
  for (int j = 0; j < 4; j++)
    Wt[(size_t)(bx + ty + j * 8) * R + by + tx] = f2bf(tile[tx][ty + j * 8]);
}

// ---------------- GEMM: C[M][N] = A[M][K](bf16) * Bt[N][K](bf16) + bias ----------------
template <bool BF16OUT>
__global__ __launch_bounds__(256) void gemm_bt_k(const u16* __restrict__ A,
                                                 const u16* __restrict__ Bt,
                                                 const float* __restrict__ bias,
                                                 void* __restrict__ Cv,
                                                 int M, int N, int K) {
  __shared__ u16 As[128 * 64];
  __shared__ u16 Bs[128 * 64];
  int tid = threadIdx.x;
  int m0 = blockIdx.y * 128, n0 = blockIdx.x * 128;
  int wave = tid >> 6, lane = tid & 63;
  int wm = (wave & 1) * 64, wn = (wave >> 1) * 64;
  int lrow = lane & 15, lk = (lane >> 4) * 8;
  int rr = lane >> 3, cb = (lane & 7) * 16;

  f32x4 acc[4][4] = {};

  for (int k0 = 0; k0 < K; k0 += 64) {
#pragma unroll
    for (int i = 0; i < 4; i++) {
      int row = wave * 32 + i * 8 + rr;
      int cc = (cb ^ ((row & 7) << 4)) >> 1;
      gload16(A + (size_t)(m0 + row) * K + k0 + cc, &As[(wave * 32 + i * 8) * 64]);
      gload16(Bt + (size_t)(n0 + row) * K + k0 + cc, &Bs[(wave * 32 + i * 8) * 64]);
    }
    __syncthreads();
#pragma unroll
    for (int kk = 0; kk < 2; kk++) {
      bf16x8 af[4], bfr[4];
#pragma unroll
      for (int i = 0; i < 4; i++) {
        int arow = wm + i * 16 + lrow;
        int ab = (arow * 128 + (kk * 32 + lk) * 2) ^ ((arow & 7) << 4);
        af[i] = *(const bf16x8*)((const char*)As + ab);
        int brow = wn + i * 16 + lrow;
        int bb = (brow * 128 + (kk * 32 + lk) * 2) ^ ((brow & 7) << 4);
        bfr[i] = *(const bf16x8*)((const char*)Bs + bb);
      }
#pragma unroll
      for (int i = 0; i < 4; i++)
#pragma unroll
        for (int j = 0; j < 4; j++)
          acc[i][j] = __builtin_amdgcn_mfma_f32_16x16x32_bf16(af[i], bfr[j], acc[i][j], 0, 0, 0);
    }
    __syncthreads();
  }
  int rg = lane >> 4;
#pragma unroll
  for (int i = 0; i < 4; i++) {
#pragma unroll
    for (int j = 0; j < 4; j++) {
      int col = n0 + wn + j * 16 + lrow;
      float bz = bias ? bias[col] : 0.f;
#pragma unroll
      for (int r = 0; r < 4; r++) {
        int row = m0 + wm + i * 16 + rg * 4 + r;
        float val = acc[i][j][r] + bz;
        if constexpr (BF16OUT)
          ((u16*)Cv)[(size_t)row * N + col] = f2bf(val);
        else
          ((float*)Cv)[(size_t)row * N + col] = val;
      }
    }
  }
}

// ---------------- RoPE on q,k (bf16 in); Q pre-scaled by 0.125*log2e ----------------
__global__ __launch_bounds__(256) void rope_qk_k(const u16* __restrict__ qkv,
                                                 u16* __restrict__ qb,
                                                 u16* __restrict__ kb) {
  int id = blockIdx.x * 256 + threadIdx.x;
  int i = id & 31;
  int h = (id >> 5) & 15;
  int t = (id >> 9) & 2047;
  int b = id >> 20;
  size_t row = (size_t)b * 2048 + t;
  const u16* base = qkv + row * 3072 + h * 64 + 2 * i;
  ushort2 qp = *(const ushort2*)(base);
  ushort2 kp = *(const ushort2*)(base + 1024);
  float qx = bf2f(qp.x), qy = bf2f(qp.y), kx = bf2f(kp.x), ky = bf2f(kp.y);
  float freq = exp2f((float)i * -0.41524101186092029f);
  float ang = (float)t * freq;
  float sv, cv;
  sincosf(ang, &sv, &cv);
  const float QS = 0.18033688011112042f;  // 0.125 * log2(e)
  size_t obase = (((size_t)(b * 16 + h) * 2048) + t) * 64 + 2 * i;
  ushort2 qo, ko;
  qo.x = f2bf((qx * cv - qy * sv) * QS); qo.y = f2bf((qx * sv + qy * cv) * QS);
  ko.x = f2bf(kx * cv - ky * sv);        ko.y = f2bf(kx * sv + ky * cv);
  *(ushort2*)(qb + obase) = qo;
  *(ushort2*)(kb + obase) = ko;
}

// ---------------- V transpose (bf16 in): (B,H,dk,T), conflict-free u32 LDS ----------------
__global__ __launch_bounds__(256) void v_trans_k(const u16* __restrict__ qkv,
                                                 u16* __restrict__ vt) {
  __shared__ unsigned tl[64][33];
  int bh = blockIdx.x;
  int t0 = blockIdx.y * 64;
  int b = bh >> 4, h = bh & 15;
  int tid = threadIdx.x;
#pragma unroll
  for (int i = 0; i < 2; i++) {
    int tr = i * 32 + (tid >> 3);
    const u16* src = qkv + ((size_t)(b * 2048 + t0 + tr)) * 3072 + 2048 + h * 64 + (tid & 7) * 8;
    u16x8 v = *(const u16x8*)src;
    const unsigned* p = (const unsigned*)&v;
    int dp0 = (tid & 7) * 4;
#pragma unroll
    for (int k = 0; k < 4; k++) tl[tr][dp0 + k] = p[k];
  }
  __syncthreads();
  u16* dst = vt + (size_t)bh * 64 * 2048;
  int t = tid & 63;
#pragma unroll
  for (int jj = 0; jj < 8; jj++) {
    int dp = jj * 4 + (tid >> 6);
    unsigned w = tl[t][dp];
    dst[(size_t)(2 * dp) * 2048 + t0 + t] = (u16)(w & 0xffff);
    dst[(size_t)(2 * dp + 1) * 2048 + t0 + t] = (u16)(w >> 16);
  }
}

// ---------------- flash attention v3: 1 wave / 32 q-rows, barrier-free ----------------
// KVBLK=32; per-wave private dbuf LDS (16KB) staged by global_load_lds, ordered
// by counted s_waitcnt vmcnt. Waves paired qt={p,63-p}: every block = 130 tiles.
#define STAGE(CUR, KV0)                                                           \
  do {                                                                            \
    _Pragma("unroll") for (int i_ = 0; i_ < 4; i_++)                              \
        gload16(Kp + (size_t)((KV0) + i_ * 8 + krow) * 64 + (kcol >> 1),          \
                kls + (CUR) * 2048 + i_ * 512);                                   \
    _Pragma("unroll") for (int i_ = 0; i_ < 4; i_++)                              \
        gload16(Vp + (size_t)(i_ * 16 + vrow) * 2048 + (KV0) + (vcol >> 1),       \
                vls + (CUR) * 2048 + i_ * 512);                                   \
  } while (0)

__global__ __launch_bounds__(256) void attn_k(const u16* __restrict__ Q,
                                              const u16* __restrict__ Kb,
                                              const u16* __restrict__ Vt,
                                              u16* __restrict__ Os) {
  __shared__ u16 sm[4][8192];  // per wave: [0..4095] K dbuf, [4096..8191] V dbuf
  const int T = 2048;
  int blk = blockIdx.x;
  int bh = blk & 31;
  int wave = threadIdx.x >> 6, lane = threadIdx.x & 63;
  int p = (blk >> 5) * 2 + (wave >> 1);   // 0..31
  int qt = (wave & 1) ? (63 - p) : p;     // 0..63
  int qw0 = qt * 32;
  int nt = qt + 1;
  int ql = lane & 31, hi = lane >> 5;
  const u16* Qp = Q + (size_t)bh * T * 64;
  const u16* Kp = Kb + (size_t)bh * T * 64;
  const u16* Vp = Vt + (size_t)bh * 64 * T;
  u16* kls = sm[wave];
  u16* vls = sm[wave] + 4096;

  // staging lane constants (pre-swizzled global source, linear LDS dest)
  int krow = lane >> 3;                                   // 0..7
  int kcol = ((lane & 7) * 16) ^ ((krow & 7) << 4);       // bytes
  int vrow = lane >> 2;                                   // 0..15
  int vcol = ((lane & 3) * 16) ^ (((vrow >> 1) & 3) << 4);

  // Q fragments (B operand): col q = ql, d-elems = ds*16 + hi*8 + j
  bf16x8 qf[4];
#pragma unroll
  for (int ds = 0; ds < 4; ds++)
    qf[ds] = *(const bf16x8*)(Qp + (size_t)(qw0 + ql) * 64 + ds * 16 + hi * 8);

  f32x16 ot0 = {}, ot1 = {};  // O^T: col q=ql, rows d (0..31 / 32..63)
  float m = -1e30f, l = 0.f;
  int qg = qw0 + ql;
  int kswz = (ql & 7) << 4;
  int vswz = ((ql >> 1) & 3) << 4;

  STAGE(0, 0);
  for (int t = 0; t < nt; ++t) {
    int cur = t & 1;
    int kv0 = t << 5;
    if (t + 1 < nt) {
      STAGE(cur ^ 1, kv0 + 32);
      asm volatile("s_waitcnt vmcnt(8)" ::: "memory");
    } else {
      asm volatile("s_waitcnt vmcnt(0)" ::: "memory");
    }
    __builtin_amdgcn_sched_barrier(0);
    const char* Kc = (const char*)kls + cur * 4096;
    const char* Vc = (const char*)vls + cur * 4096;
    // ---- QK^T (swapped): S^T[k][q], scale pre-folded into Q ----
    f32x16 st = {};
#pragma unroll
    for (int ds = 0; ds < 4; ds++) {
      bf16x8 kf = *(const bf16x8*)(Kc + ql * 128 + ((ds * 32 + hi * 16) ^ kswz));
      st = __builtin_amdgcn_mfma_f32_32x32x16_bf16(kf, qf[ds], st, 0, 0, 0);
    }
    // ---- causal mask: only the diagonal tile ----
    if (t == qt) {
#pragma unroll
      for (int r = 0; r < 16; r++) {
        int k = kv0 + ((r & 3) + 8 * (r >> 2) + 4 * hi);
        if (k > qg) st[r] = -1e30f;
      }
    }
    // ---- softmax (exp2 domain, lane-local rows, one cross-lane swap) ----
    float t0_ = fmaxf(fmaxf(st[0], st[1]), fmaxf(st[2], st[3]));
    float t1_ = fmaxf(fmaxf(st[4], st[5]), fmaxf(st[6], st[7]));
    float t2_ = fmaxf(fmaxf(st[8], st[9]), fmaxf(st[10], st[11]));
    float t3_ = fmaxf(fmaxf(st[12], st[13]), fmaxf(st[14], st[15]));
    float tmax = fmaxf(fmaxf(t0_, t1_), fmaxf(t2_, t3_));
    tmax = fmaxf(tmax, __shfl_xor(tmax, 32));
    bool skip = __all(tmax <= m + 11.5409f) != 0;  // defer-max (T13), THR=8*log2e
    if (!skip) {
      float mn = fmaxf(m, tmax);
      float corr = exp2_(m - mn);
      m = mn;
      l *= corr;
#pragma unroll
      for (int r = 0; r < 16; r++) { ot0[r] *= corr; ot1[r] *= corr; }
    }
#pragma unroll
    for (int r = 0; r < 16; r++) st[r] = exp2_(st[r] - m);
    float s0_ = ((st[0] + st[1]) + (st[2] + st[3])) + ((st[4] + st[5]) + (st[6] + st[7]));
    float s1_ = ((st[8] + st[9]) + (st[10] + st[11])) + ((st[12] + st[13]) + (st[14] + st[15]));
    float ts = s0_ + s1_;
    ts += __shfl_xor(ts, 32);
    l += ts;
    // ---- pack P^T -> PV B-fragments (8 cvt_pk + 8 shfl) ----
    unsigned w[8], x[8];
#pragma unroll
    for (int j = 0; j < 8; j++) w[j] = cvtpk(st[2 * j], st[2 * j + 1]);
#pragma unroll
    for (int j = 0; j < 8; j++) x[j] = (unsigned)__shfl_xor((int)w[j], 32);
    U8 pf0, pf1;
    pf0.u[0] = hi ? x[2] : w[0]; pf0.u[1] = hi ? x[3] : w[1];
    pf0.u[2] = hi ? w[2] : x[0]; pf0.u[3] = hi ? w[3] : x[1];
    pf1.u[0] = hi ? x[6] : w[4]; pf1.u[1] = hi ? x[7] : w[5];
    pf1.u[2] = hi ? w[6] : x[4]; pf1.u[3] = hi ? w[7] : x[5];
    // ---- PV: O^T[d][q] += V^T[d][k] * P^T[k][q] ----
    ot0 = __builtin_amdgcn_mfma_f32_32x32x16_bf16(
        *(const bf16x8*)(Vc + ql * 64 + ((16 * hi) ^ vswz)), pf0.v, ot0, 0, 0, 0);
    ot0 = __builtin_amdgcn_mfma_f32_32x32x16_bf16(
        *(const bf16x8*)(Vc + ql * 64 + ((32 + 16 * hi) ^ vswz)), pf1.v, ot0, 0, 0, 0);
    ot1 = __builtin_amdgcn_mfma_f32_32x32x16_bf16(
        *(const bf16x8*)(Vc + (32 + ql) * 64 + ((16 * hi) ^ vswz)), pf0.v, ot1, 0, 0, 0);
    ot1 = __builtin_amdgcn_mfma_f32_32x32x16_bf16(
        *(const bf16x8*)(Vc + (32 + ql) * 64 + ((32 + 16 * hi) ^ vswz)), pf1.v, ot1, 0, 0, 0);
    __builtin_amdgcn_sched_barrier(0);
  }

  // ---- epilogue: O = O^T/l, fused head re-interleave into (B*T, C) bf16 ----
  float inv = 1.f / l;
  int b = bh >> 4, h = bh & 15;
  u16* orow = Os + ((size_t)(b * T + qg)) * 1024 + h * 64;
#pragma unroll
  for (int j = 0; j < 4; j++) {
    ushort4 o;
    o.x = f2bf(ot0[4 * j + 0] * inv); o.y = f2bf(ot0[4 * j + 1] * inv);
    o.z = f2bf(ot0[4 * j + 2] * inv); o.w = f2bf(ot0[4 * j + 3] * inv);
    *(ushort4*)(orow + 8 * j + 4 * hi) = o;
    ushort4 q;
    q.x = f2bf(ot1[4 * j + 0] * inv); q.y = f2bf(ot1[4 * j + 1] * inv);
    q.z = f2bf(ot1[4 * j + 2] * inv); q.w = f2bf(ot1[4 * j + 3] * inv);
    *(ushort4*)(orow + 32 + 8 * j + 4 * hi) = q;
  }
}

extern "C" void kernel_launch(void* const* d_in, const int* in_sizes, int n_in,
                              void* d_out, int out_size, void* d_ws, size_t ws_size,
                              hipStream_t stream) {
  const float* x      = (const float*)d_in[0];
  const float* W_qkv  = (const float*)d_in[1];
  const float* b_qkv  = (const float*)d_in[2];
  const float* W_proj = (const float*)d_in[3];
  const float* b_proj = (const float*)d_in[4];
  float* out = (float*)d_out;

  const int B = 2, T = 2048, C = 1024;
  const int M = B * T;  // 4096

  char* ws = (char*)d_ws;
  u16* xb     = (u16*)(ws);                       // 8 MB
  u16* wqkvt  = (u16*)(ws + (8ull << 20));        // 6 MB
  u16* wprojt = (u16*)(ws + (14ull << 20));       // 2 MB
  u16* qb     = (u16*)(ws + (16ull << 20));       // 8 MB
  u16* kb     = (u16*)(ws + (24ull << 20));       // 8 MB
  u16* vt     = (u16*)(ws + (32ull << 20));       // 8 MB
  u16* sc     = (u16*)(ws + (40ull << 20));       // 8 MB
  u16* qkvb   = (u16*)(ws + (48ull << 20));       // 24 MB (bf16 qkv)

  cast_x_k<<<(M * C / 8 + 255) / 256, 256, 0, stream>>>(x, xb, M * C / 8);
  tcast_k<<<dim3(3 * C / 32, C / 32), 256, 0, stream>>>(W_qkv, wqkvt, C, 3 * C);
  tcast_k<<<dim3(C / 32, C / 32), 256, 0, stream>>>(W_proj, wprojt, C, C);
  gemm_bt_k<true><<<dim3(3 * C / 128, M / 128), 256, 0, stream>>>(xb, wqkvt, b_qkv, qkvb, M, 3 * C, C);
  rope_qk_k<<<(B * T * 16 * 32) / 256, 256, 0, stream>>>(qkvb, qb, kb);
  v_trans_k<<<dim3(B * 16, T / 64), 256, 0, stream>>>(qkvb, vt);
  attn_k<<<512, 256, 0, stream>>>(qb, kb, vt, sc);
  gemm_bt_k<false><<<dim3(C / 128, M / 128), 256, 0, stream>>>(sc, wprojt, b_proj, out, M, C, C);
}